// Round 8
// baseline (678.426 us; speedup 1.0000x reference)
//
#include <hip/hip_runtime.h>
#include <hip/hip_bf16.h>
#include <stdint.h>

#define B_ 4
#define T_ 4096
#define C_ 1024
#define D_ 1024
#define NC_ 64   // chunks over T
#define LC_ 64   // chunk length

typedef __bf16 bf16x8 __attribute__((ext_vector_type(8)));
typedef float  f32x4  __attribute__((ext_vector_type(4)));

__device__ __forceinline__ unsigned short f2bf(float f) {
    union { float f; unsigned u; } c; c.f = f;
    return (unsigned short)((c.u + 0x7fffu + ((c.u >> 16) & 1u)) >> 16);  // RNE
}

// ---------------- cast fp32 -> bf16 (weights) ----------------
__global__ void cast_bf16_kernel(const float* __restrict__ s, unsigned short* __restrict__ d) {
    int i = blockIdx.x * blockDim.x + threadIdx.x;   // groups of 4; n = 1M elems
    float4 v = *reinterpret_cast<const float4*>(s + ((size_t)i << 2));
    ushort4 o;
    o.x = f2bf(v.x); o.y = f2bf(v.y); o.z = f2bf(v.z); o.w = f2bf(v.w);
    *reinterpret_cast<ushort4*>(d + ((size_t)i << 2)) = o;
}

// ---------------- time-shift mix -> xk/xv/xr bf16 (rows = one batch's T rows) ----
__global__ void mix_cast_kernel(const float* __restrict__ x,
                                const float* __restrict__ mk,
                                const float* __restrict__ mv,
                                const float* __restrict__ mr,
                                unsigned short* __restrict__ xk,
                                unsigned short* __restrict__ xv,
                                unsigned short* __restrict__ xr) {
    int i = blockIdx.x * blockDim.x + threadIdx.x;   // groups of 4 elems
    int base = i << 2;
    int c = base & (C_ - 1);
    int m = base >> 10;          // row within this launch's region
    int t = m & (T_ - 1);        // row within batch
    float4 xc = *reinterpret_cast<const float4*>(x + base);
    float4 xp = make_float4(0.f, 0.f, 0.f, 0.f);
    if (t != 0) xp = *reinterpret_cast<const float4*>(x + base - C_);
    float4 k4 = *reinterpret_cast<const float4*>(mk + c);
    float4 v4 = *reinterpret_cast<const float4*>(mv + c);
    float4 r4 = *reinterpret_cast<const float4*>(mr + c);
    ushort4 ok, ov, orr;
    ok.x  = f2bf(xp.x + k4.x * (xc.x - xp.x));
    ok.y  = f2bf(xp.y + k4.y * (xc.y - xp.y));
    ok.z  = f2bf(xp.z + k4.z * (xc.z - xp.z));
    ok.w  = f2bf(xp.w + k4.w * (xc.w - xp.w));
    ov.x  = f2bf(xp.x + v4.x * (xc.x - xp.x));
    ov.y  = f2bf(xp.y + v4.y * (xc.y - xp.y));
    ov.z  = f2bf(xp.z + v4.z * (xc.z - xp.z));
    ov.w  = f2bf(xp.w + v4.w * (xc.w - xp.w));
    orr.x = f2bf(xp.x + r4.x * (xc.x - xp.x));
    orr.y = f2bf(xp.y + r4.y * (xc.y - xp.y));
    orr.z = f2bf(xp.z + r4.z * (xc.z - xp.z));
    orr.w = f2bf(xp.w + r4.w * (xc.w - xp.w));
    *reinterpret_cast<ushort4*>(xk + base) = ok;
    *reinterpret_cast<ushort4*>(xv + base) = ov;
    *reinterpret_cast<ushort4*>(xr + base) = orr;
}

// ---------------- bt-GEMM: C[m][n] = sum_k A[m][k]*Bw[n][k] ----------------
// A: [M][1024] bf16, Bw: [1024][1024] bf16, C: fp32. 128x128 tile, BK=32, 4 waves.
// Reg-staged LDS (uint4 load -> ds_write_b128): no global_load_lds (crash-suspect A/B).
template<bool SIG>
__global__ __launch_bounds__(256) void gemm_bt(const unsigned short* __restrict__ A,
                                               const unsigned short* __restrict__ Bw,
                                               float* __restrict__ Cm) {
    __shared__ __align__(16) unsigned short As[128 * 32];
    __shared__ __align__(16) unsigned short Bs[128 * 32];
    const int tid  = threadIdx.x;
    const int lane = tid & 63;
    const int wid  = tid >> 6;
    const int bn = (blockIdx.x & 7) << 7;
    const int bm = (blockIdx.x >> 3) << 7;
    const int wr = (wid >> 1) * 64;
    const int wc = (wid & 1) * 64;

    f32x4 acc[4][4] = {};

    // staging: thread loads 16B at row r0 (+64), k-chunk ck; ds_write to matching slot
    const int r0 = tid >> 2;
    const int ck = (tid & 3) * 8;
    const unsigned short* ga = A  + (size_t)(bm + r0) * 1024 + ck;
    const unsigned short* gb = Bw + (size_t)(bn + r0) * 1024 + ck;

    uint4 ra0 = *reinterpret_cast<const uint4*>(ga);
    uint4 ra1 = *reinterpret_cast<const uint4*>(ga + 64 * 1024);
    uint4 rb0 = *reinterpret_cast<const uint4*>(gb);
    uint4 rb1 = *reinterpret_cast<const uint4*>(gb + 64 * 1024);

    const int arow = wr + (lane & 15);
    const int brow = wc + (lane & 15);
    const int ko   = (lane >> 4) * 8;
    const int wofs = r0 * 32 + ck;

    for (int ks = 0; ks < 32; ++ks) {
        __syncthreads();
        *reinterpret_cast<uint4*>(&As[wofs])        = ra0;
        *reinterpret_cast<uint4*>(&As[wofs + 2048]) = ra1;   // +64 rows
        *reinterpret_cast<uint4*>(&Bs[wofs])        = rb0;
        *reinterpret_cast<uint4*>(&Bs[wofs + 2048]) = rb1;
        __syncthreads();
        if (ks < 31) {   // prefetch next K-slab into regs, overlaps MFMA below
            ga += 32; gb += 32;
            ra0 = *reinterpret_cast<const uint4*>(ga);
            ra1 = *reinterpret_cast<const uint4*>(ga + 64 * 1024);
            rb0 = *reinterpret_cast<const uint4*>(gb);
            rb1 = *reinterpret_cast<const uint4*>(gb + 64 * 1024);
        }
        bf16x8 af[4], bfr[4];
        #pragma unroll
        for (int i = 0; i < 4; ++i) {
            af[i]  = *reinterpret_cast<const bf16x8*>(&As[(arow + i * 16) * 32 + ko]);
            bfr[i] = *reinterpret_cast<const bf16x8*>(&Bs[(brow + i * 16) * 32 + ko]);
        }
        #pragma unroll
        for (int i = 0; i < 4; ++i)
            #pragma unroll
            for (int j = 0; j < 4; ++j)
                acc[i][j] = __builtin_amdgcn_mfma_f32_16x16x32_bf16(af[i], bfr[j], acc[i][j], 0, 0, 0);
    }

    const int row0 = bm + wr + (lane >> 4) * 4;
    const int col0 = bn + wc + (lane & 15);
    #pragma unroll
    for (int i = 0; i < 4; ++i)
        #pragma unroll
        for (int j = 0; j < 4; ++j)
            #pragma unroll
            for (int r = 0; r < 4; ++r) {
                float vv = acc[i][j][r];
                if (SIG) vv = 1.0f / (1.0f + __expf(-vv));
                Cm[(size_t)(row0 + i * 16 + r) * 1024 + col0 + j * 16] = vv;
            }
}

// ---------------- WKV pass A: per-chunk contribution (init 0,0,-inf) ----------------
__global__ void wkv_chunk(const float* __restrict__ k, const float* __restrict__ v,
                          const float* __restrict__ td,
                          float* __restrict__ ca, float* __restrict__ cb, float* __restrict__ cp,
                          int NB) {
    int gid = blockIdx.x * 256 + threadIdx.x;  // NB*NC*D threads
    int d   = gid & (D_ - 1);
    int rem = gid >> 10;
    int j   = rem & (NC_ - 1);
    int b   = rem >> 6;
    float w = -__expf(td[d]);
    size_t base = ((size_t)(b * T_ + j * LC_)) * D_ + d;
    float aa = 0.f, bb = 0.f, pp = -1e38f;
    for (int t = 0; t < LC_; ++t) {
        float kt = k[base + (size_t)t * D_];
        float vt = v[base + (size_t)t * D_];
        float ww = pp + w;
        float p  = fmaxf(ww, kt);
        float e1 = __expf(ww - p);
        float e2 = __expf(kt - p);
        aa = e1 * aa + e2 * vt;
        bb = e1 * bb + e2;
        pp = p;
    }
    int ch  = (b << 10) + d;
    int idx = j * (NB << 10) + ch;
    ca[idx] = aa;
    cb[idx] = bb;
    cp[idx] = pp;
}

// ---------------- WKV pass B: combine over chunks, store chunk-entry states ----------
__global__ void wkv_scan(const float* __restrict__ ca, const float* __restrict__ cb,
                         const float* __restrict__ cp, const float* __restrict__ td,
                         float* __restrict__ sa, float* __restrict__ sb, float* __restrict__ sp,
                         int NB) {
    int ch = blockIdx.x * 256 + threadIdx.x;  // NB*D channels
    int d  = ch & (D_ - 1);
    float w  = -__expf(td[d]);
    float wL = w * (float)LC_;
    float A = 0.f, Bv = 0.f, P = -1e38f;
    int stride = NB << 10;
    for (int j = 0; j < NC_; ++j) {
        int idx = j * stride + ch;
        sa[idx] = A; sb[idx] = Bv; sp[idx] = P;
        float a2 = ca[idx], b2 = cb[idx], p2 = cp[idx];
        float Pd = P + wL;                    // decay state across a whole chunk
        float pm = fmaxf(Pd, p2);
        float e1 = __expf(Pd - pm);
        float e2 = __expf(p2 - pm);
        A  = e1 * A  + e2 * a2;
        Bv = e1 * Bv + e2 * b2;
        P  = pm;
    }
}

// ---------------- WKV pass C: emit y = sr * wkv as bf16 ----------------
__global__ void wkv_emit(const float* __restrict__ k, const float* __restrict__ v,
                         const float* __restrict__ sr, const float* __restrict__ td,
                         const float* __restrict__ tf,
                         const float* __restrict__ sa, const float* __restrict__ sb,
                         const float* __restrict__ sp,
                         unsigned short* __restrict__ ybf, int NB) {
    int gid = blockIdx.x * 256 + threadIdx.x;
    int d   = gid & (D_ - 1);
    int rem = gid >> 10;
    int j   = rem & (NC_ - 1);
    int b   = rem >> 6;
    int ch  = (b << 10) + d;
    float w = -__expf(td[d]);
    float u = tf[d];
    int idx = j * (NB << 10) + ch;
    float aa = sa[idx], bb = sb[idx], pp = sp[idx];
    size_t base = ((size_t)(b * T_ + j * LC_)) * D_ + d;
    for (int t = 0; t < LC_; ++t) {
        size_t o = base + (size_t)t * D_;
        float kt = k[o];
        float vt = v[o];
        float ww = u + kt;
        float p  = fmaxf(pp, ww);
        float e1 = __expf(pp - p);
        float e2 = __expf(ww - p);
        float y  = (e1 * aa + e2 * vt) / (e1 * bb + e2);
        ybf[o] = f2bf(sr[o] * y);
        float ww2 = pp + w;
        float p2  = fmaxf(ww2, kt);
        float e1b = __expf(ww2 - p2);
        float e2b = __expf(kt - p2);
        aa = e1b * aa + e2b * vt;
        bb = e1b * bb + e2b;
        pp = p2;
    }
}

extern "C" void kernel_launch(void* const* d_in, const int* in_sizes, int n_in,
                              void* d_out, int out_size, void* d_ws, size_t ws_size,
                              hipStream_t stream) {
    const float* x  = (const float*)d_in[0];
    const float* td = (const float*)d_in[1];
    const float* tf = (const float*)d_in[2];
    const float* mk = (const float*)d_in[3];
    const float* mv = (const float*)d_in[4];
    const float* mr = (const float*)d_in[5];
    const float* Wk = (const float*)d_in[6];
    const float* Wv = (const float*)d_in[7];
    const float* Wr = (const float*)d_in[8];
    const float* Wo = (const float*)d_in[9];
    float* out = (float*)d_out;

    char* ws = (char*)d_ws;
    unsigned short* wkbf = (unsigned short*)(ws + ((size_t)0 << 20));
    unsigned short* wvbf = (unsigned short*)(ws + ((size_t)2 << 20));
    unsigned short* wrbf = (unsigned short*)(ws + ((size_t)4 << 20));
    unsigned short* wobf = (unsigned short*)(ws + ((size_t)6 << 20));

    cast_bf16_kernel<<<1024, 256, 0, stream>>>(Wk, wkbf);
    cast_bf16_kernel<<<1024, 256, 0, stream>>>(Wv, wvbf);
    cast_bf16_kernel<<<1024, 256, 0, stream>>>(Wr, wrbf);
    cast_bf16_kernel<<<1024, 256, 0, stream>>>(Wo, wobf);

    if (ws_size >= ((size_t)320 << 20)) {
        // ---- full-batch path (296 MB) : 12 dispatches ----
        unsigned short* xk = (unsigned short*)(ws + ((size_t)8  << 20));
        unsigned short* xv = (unsigned short*)(ws + ((size_t)40 << 20));
        unsigned short* xr = (unsigned short*)(ws + ((size_t)72 << 20));
        float* kb  = (float*)(ws + ((size_t)104 << 20));
        float* vb  = (float*)(ws + ((size_t)168 << 20));
        float* srb = (float*)(ws + ((size_t)232 << 20));
        unsigned short* ybf = xk;                      // dead after GEMM #1
        float* ca = (float*)(ws + ((size_t)40 << 20)); // xv region, dead after GEMM #2
        float* cb = ca + (1u << 18);
        float* cp = cb + (1u << 18);
        float* sa = cp + (1u << 18);
        float* sb = sa + (1u << 18);
        float* sp = sb + (1u << 18);

        mix_cast_kernel<<<16384, 256, 0, stream>>>(x, mk, mv, mr, xk, xv, xr);
        gemm_bt<false><<<1024, 256, 0, stream>>>(xk, wkbf, kb);
        gemm_bt<false><<<1024, 256, 0, stream>>>(xv, wvbf, vb);
        gemm_bt<true ><<<1024, 256, 0, stream>>>(xr, wrbf, srb);
        wkv_chunk<<<1024, 256, 0, stream>>>(kb, vb, td, ca, cb, cp, 4);
        wkv_scan<<<16, 256, 0, stream>>>(ca, cb, cp, td, sa, sb, sp, 4);
        wkv_emit<<<1024, 256, 0, stream>>>(kb, vb, srb, td, tf, sa, sb, sp, ybf, 4);
        gemm_bt<false><<<1024, 256, 0, stream>>>(ybf, wobf, out);
    } else {
        // ---- per-batch path (~82 MB peak) : 36 dispatches ----
        unsigned short* xk = (unsigned short*)(ws + ((size_t)8  << 20));  // 8 MB
        unsigned short* xv = (unsigned short*)(ws + ((size_t)16 << 20));
        unsigned short* xr = (unsigned short*)(ws + ((size_t)24 << 20));
        float* kb  = (float*)(ws + ((size_t)32 << 20));                   // 16 MB
        float* vb  = (float*)(ws + ((size_t)48 << 20));
        float* srb = (float*)(ws + ((size_t)64 << 20));
        float* ca  = (float*)(ws + ((size_t)80 << 20));                   // 256 KB each
        float* cb  = ca + (1u << 16);
        float* cp  = cb + (1u << 16);
        float* sa  = cp + (1u << 16);
        float* sb  = sa + (1u << 16);
        float* sp  = sb + (1u << 16);
        unsigned short* ybf = xk;

        for (int b = 0; b < B_; ++b) {
            const float* xb = x + (size_t)b * T_ * C_;
            float* outb = out + (size_t)b * T_ * C_;
            mix_cast_kernel<<<4096, 256, 0, stream>>>(xb, mk, mv, mr, xk, xv, xr);
            gemm_bt<false><<<256, 256, 0, stream>>>(xk, wkbf, kb);
            gemm_bt<false><<<256, 256, 0, stream>>>(xv, wvbf, vb);
            gemm_bt<true ><<<256, 256, 0, stream>>>(xr, wrbf, srb);
            wkv_chunk<<<256, 256, 0, stream>>>(kb, vb, td, ca, cb, cp, 1);
            wkv_scan<<<4, 256, 0, stream>>>(ca, cb, cp, td, sa, sb, sp, 1);
            wkv_emit<<<256, 256, 0, stream>>>(kb, vb, srb, td, tf, sa, sb, sp, ybf, 1);
            gemm_bt<false><<<256, 256, 0, stream>>>(ybf, wobf, outb);
        }
    }
}

// Round 15
// 478.431 us; speedup vs baseline: 1.4180x; 1.4180x over previous
//
#include <hip/hip_runtime.h>
#include <hip/hip_bf16.h>
#include <stdint.h>

#define B_ 4
#define T_ 4096
#define C_ 1024
#define D_ 1024
#define NC_ 64   // chunks over T
#define LC_ 64   // chunk length

typedef __bf16 bf16x8 __attribute__((ext_vector_type(8)));
typedef float  f32x4  __attribute__((ext_vector_type(4)));

__device__ __forceinline__ unsigned short f2bf(float f) {
    union { float f; unsigned u; } c; c.f = f;
    return (unsigned short)((c.u + 0x7fffu + ((c.u >> 16) & 1u)) >> 16);  // RNE
}

// ---------------- cast fp32 -> bf16 (weights) ----------------
__global__ void cast_bf16_kernel(const float* __restrict__ s, unsigned short* __restrict__ d) {
    int i = blockIdx.x * blockDim.x + threadIdx.x;   // groups of 4; n = 1M elems
    float4 v = *reinterpret_cast<const float4*>(s + ((size_t)i << 2));
    ushort4 o;
    o.x = f2bf(v.x); o.y = f2bf(v.y); o.z = f2bf(v.z); o.w = f2bf(v.w);
    *reinterpret_cast<ushort4*>(d + ((size_t)i << 2)) = o;
}

// ---------------- time-shift mix -> xk/xv/xr bf16 ----------------
__global__ void mix_cast_kernel(const float* __restrict__ x,
                                const float* __restrict__ mk,
                                const float* __restrict__ mv,
                                const float* __restrict__ mr,
                                unsigned short* __restrict__ xk,
                                unsigned short* __restrict__ xv,
                                unsigned short* __restrict__ xr) {
    int i = blockIdx.x * blockDim.x + threadIdx.x;   // groups of 4 elems
    int base = i << 2;
    int c = base & (C_ - 1);
    int m = base >> 10;          // row within this launch's region
    int t = m & (T_ - 1);        // row within batch
    float4 xc = *reinterpret_cast<const float4*>(x + base);
    float4 xp = make_float4(0.f, 0.f, 0.f, 0.f);
    if (t != 0) xp = *reinterpret_cast<const float4*>(x + base - C_);
    float4 k4 = *reinterpret_cast<const float4*>(mk + c);
    float4 v4 = *reinterpret_cast<const float4*>(mv + c);
    float4 r4 = *reinterpret_cast<const float4*>(mr + c);
    ushort4 ok, ov, orr;
    ok.x  = f2bf(xp.x + k4.x * (xc.x - xp.x));
    ok.y  = f2bf(xp.y + k4.y * (xc.y - xp.y));
    ok.z  = f2bf(xp.z + k4.z * (xc.z - xp.z));
    ok.w  = f2bf(xp.w + k4.w * (xc.w - xp.w));
    ov.x  = f2bf(xp.x + v4.x * (xc.x - xp.x));
    ov.y  = f2bf(xp.y + v4.y * (xc.y - xp.y));
    ov.z  = f2bf(xp.z + v4.z * (xc.z - xp.z));
    ov.w  = f2bf(xp.w + v4.w * (xc.w - xp.w));
    orr.x = f2bf(xp.x + r4.x * (xc.x - xp.x));
    orr.y = f2bf(xp.y + r4.y * (xc.y - xp.y));
    orr.z = f2bf(xp.z + r4.z * (xc.z - xp.z));
    orr.w = f2bf(xp.w + r4.w * (xc.w - xp.w));
    *reinterpret_cast<ushort4*>(xk + base) = ok;
    *reinterpret_cast<ushort4*>(xv + base) = ov;
    *reinterpret_cast<ushort4*>(xr + base) = orr;
}

// ---------------- bt-GEMM: C[m][n] = sum_k A[m][k]*Bw[n][k] ----------------
// A: [M][1024] bf16, Bw: [1024][1024] bf16, C: fp32. 128x128 tile, BK=32, 4 waves.
template<bool SIG>
__global__ __launch_bounds__(256) void gemm_bt(const unsigned short* __restrict__ A,
                                               const unsigned short* __restrict__ Bw,
                                               float* __restrict__ Cm) {
    __shared__ __align__(16) unsigned short As[128 * 32];
    __shared__ __align__(16) unsigned short Bs[128 * 32];
    const int tid  = threadIdx.x;
    const int lane = tid & 63;
    const int wid  = tid >> 6;
    const int bn = (blockIdx.x & 7) << 7;
    const int bm = (blockIdx.x >> 3) << 7;
    const int wr = (wid >> 1) * 64;
    const int wc = (wid & 1) * 64;

    f32x4 acc[4][4] = {};

    // staging: thread loads 16B at row r0 (+64), k-chunk ck; ds_write to matching slot
    const int r0 = tid >> 2;
    const int ck = (tid & 3) * 8;
    const unsigned short* ga = A  + (size_t)(bm + r0) * 1024 + ck;
    const unsigned short* gb = Bw + (size_t)(bn + r0) * 1024 + ck;

    uint4 ra0 = *reinterpret_cast<const uint4*>(ga);
    uint4 ra1 = *reinterpret_cast<const uint4*>(ga + 64 * 1024);
    uint4 rb0 = *reinterpret_cast<const uint4*>(gb);
    uint4 rb1 = *reinterpret_cast<const uint4*>(gb + 64 * 1024);

    const int arow = wr + (lane & 15);
    const int brow = wc + (lane & 15);
    const int ko   = (lane >> 4) * 8;
    const int wofs = r0 * 32 + ck;

    for (int ks = 0; ks < 32; ++ks) {
        __syncthreads();
        *reinterpret_cast<uint4*>(&As[wofs])        = ra0;
        *reinterpret_cast<uint4*>(&As[wofs + 2048]) = ra1;   // +64 rows
        *reinterpret_cast<uint4*>(&Bs[wofs])        = rb0;
        *reinterpret_cast<uint4*>(&Bs[wofs + 2048]) = rb1;
        __syncthreads();
        if (ks < 31) {   // prefetch next K-slab into regs, overlaps MFMA below
            ga += 32; gb += 32;
            ra0 = *reinterpret_cast<const uint4*>(ga);
            ra1 = *reinterpret_cast<const uint4*>(ga + 64 * 1024);
            rb0 = *reinterpret_cast<const uint4*>(gb);
            rb1 = *reinterpret_cast<const uint4*>(gb + 64 * 1024);
        }
        bf16x8 af[4], bfr[4];
        #pragma unroll
        for (int i = 0; i < 4; ++i) {
            af[i]  = *reinterpret_cast<const bf16x8*>(&As[(arow + i * 16) * 32 + ko]);
            bfr[i] = *reinterpret_cast<const bf16x8*>(&Bs[(brow + i * 16) * 32 + ko]);
        }
        #pragma unroll
        for (int i = 0; i < 4; ++i)
            #pragma unroll
            for (int j = 0; j < 4; ++j)
                acc[i][j] = __builtin_amdgcn_mfma_f32_16x16x32_bf16(af[i], bfr[j], acc[i][j], 0, 0, 0);
    }

    const int row0 = bm + wr + (lane >> 4) * 4;
    const int col0 = bn + wc + (lane & 15);
    #pragma unroll
    for (int i = 0; i < 4; ++i)
        #pragma unroll
        for (int j = 0; j < 4; ++j)
            #pragma unroll
            for (int r = 0; r < 4; ++r) {
                float vv = acc[i][j][r];
                if (SIG) vv = 1.0f / (1.0f + __expf(-vv));
                Cm[(size_t)(row0 + i * 16 + r) * 1024 + col0 + j * 16] = vv;
            }
}

// ---------------- WKV pass A: per-chunk contribution (init 0,0,-inf) ----------------
__global__ void wkv_chunk(const float* __restrict__ k, const float* __restrict__ v,
                          const float* __restrict__ td,
                          float* __restrict__ ca, float* __restrict__ cb, float* __restrict__ cp,
                          int NB) {
    int gid = blockIdx.x * 256 + threadIdx.x;  // NB*NC*D threads
    int d   = gid & (D_ - 1);
    int rem = gid >> 10;
    int j   = rem & (NC_ - 1);
    int b   = rem >> 6;
    float w = -__expf(td[d]);
    size_t base = ((size_t)(b * T_ + j * LC_)) * D_ + d;
    float aa = 0.f, bb = 0.f, pp = -1e38f;
    for (int t = 0; t < LC_; ++t) {
        float kt = k[base + (size_t)t * D_];
        float vt = v[base + (size_t)t * D_];
        float ww = pp + w;
        float p  = fmaxf(ww, kt);
        float e1 = __expf(ww - p);
        float e2 = __expf(kt - p);
        aa = e1 * aa + e2 * vt;
        bb = e1 * bb + e2;
        pp = p;
    }
    int ch  = (b << 10) + d;
    int idx = j * (NB << 10) + ch;
    ca[idx] = aa;
    cb[idx] = bb;
    cp[idx] = pp;
}

// ---------------- WKV pass B: combine over chunks, store chunk-entry states ----------
__global__ void wkv_scan(const float* __restrict__ ca, const float* __restrict__ cb,
                         const float* __restrict__ cp, const float* __restrict__ td,
                         float* __restrict__ sa, float* __restrict__ sb, float* __restrict__ sp,
                         int NB) {
    int ch = blockIdx.x * 256 + threadIdx.x;  // NB*D channels
    int d  = ch & (D_ - 1);
    float w  = -__expf(td[d]);
    float wL = w * (float)LC_;
    float A = 0.f, Bv = 0.f, P = -1e38f;
    int stride = NB << 10;
    for (int j = 0; j < NC_; ++j) {
        int idx = j * stride + ch;
        sa[idx] = A; sb[idx] = Bv; sp[idx] = P;
        float a2 = ca[idx], b2 = cb[idx], p2 = cp[idx];
        float Pd = P + wL;                    // decay state across a whole chunk
        float pm = fmaxf(Pd, p2);
        float e1 = __expf(Pd - pm);
        float e2 = __expf(p2 - pm);
        A  = e1 * A  + e2 * a2;
        Bv = e1 * Bv + e2 * b2;
        P  = pm;
    }
}

// ---------------- WKV pass C: emit y = sr * wkv as bf16 ----------------
__global__ void wkv_emit(const float* __restrict__ k, const float* __restrict__ v,
                         const float* __restrict__ sr, const float* __restrict__ td,
                         const float* __restrict__ tf,
                         const float* __restrict__ sa, const float* __restrict__ sb,
                         const float* __restrict__ sp,
                         unsigned short* __restrict__ ybf, int NB) {
    int gid = blockIdx.x * 256 + threadIdx.x;
    int d   = gid & (D_ - 1);
    int rem = gid >> 10;
    int j   = rem & (NC_ - 1);
    int b   = rem >> 6;
    int ch  = (b << 10) + d;
    float w = -__expf(td[d]);
    float u = tf[d];
    int idx = j * (NB << 10) + ch;
    float aa = sa[idx], bb = sb[idx], pp = sp[idx];
    size_t base = ((size_t)(b * T_ + j * LC_)) * D_ + d;
    for (int t = 0; t < LC_; ++t) {
        size_t o = base + (size_t)t * D_;
        float kt = k[o];
        float vt = v[o];
        float ww = u + kt;
        float p  = fmaxf(pp, ww);
        float e1 = __expf(pp - p);
        float e2 = __expf(ww - p);
        float y  = (e1 * aa + e2 * vt) / (e1 * bb + e2);
        ybf[o] = f2bf(sr[o] * y);
        float ww2 = pp + w;
        float p2  = fmaxf(ww2, kt);
        float e1b = __expf(ww2 - p2);
        float e2b = __expf(kt - p2);
        aa = e1b * aa + e2b * vt;
        bb = e1b * bb + e2b;
        pp = p2;
    }
}

extern "C" void kernel_launch(void* const* d_in, const int* in_sizes, int n_in,
                              void* d_out, int out_size, void* d_ws, size_t ws_size,
                              hipStream_t stream) {
    const float* x  = (const float*)d_in[0];
    const float* td = (const float*)d_in[1];
    const float* tf = (const float*)d_in[2];
    const float* mk = (const float*)d_in[3];
    const float* mv = (const float*)d_in[4];
    const float* mr = (const float*)d_in[5];
    const float* Wk = (const float*)d_in[6];
    const float* Wv = (const float*)d_in[7];
    const float* Wr = (const float*)d_in[8];
    const float* Wo = (const float*)d_in[9];
    float* out = (float*)d_out;

    char* ws = (char*)d_ws;
    unsigned short* wkbf = (unsigned short*)(ws + ((size_t)0 << 20));
    unsigned short* wvbf = (unsigned short*)(ws + ((size_t)2 << 20));
    unsigned short* wrbf = (unsigned short*)(ws + ((size_t)4 << 20));
    unsigned short* wobf = (unsigned short*)(ws + ((size_t)6 << 20));

    cast_bf16_kernel<<<1024, 256, 0, stream>>>(Wk, wkbf);
    cast_bf16_kernel<<<1024, 256, 0, stream>>>(Wv, wvbf);
    cast_bf16_kernel<<<1024, 256, 0, stream>>>(Wr, wrbf);
    cast_bf16_kernel<<<1024, 256, 0, stream>>>(Wo, wobf);

    if (ws_size >= ((size_t)240 << 20)) {
        // ---- full-batch path, 238 MiB peak via aliasing : 12 dispatches ----
        // 8-40: xk | 40-72: xv | 72-104: xr | 104-168: kb | 168-232: vb
        // srb (fp32 64MiB) overlays xk+xv (dead after GEMMs k,v)
        // ybf (bf16 32MiB) overlays xr (dead after GEMM r)
        // chunk/scan bufs 6 MiB at 232-238
        unsigned short* xk = (unsigned short*)(ws + ((size_t)8  << 20));
        unsigned short* xv = (unsigned short*)(ws + ((size_t)40 << 20));
        unsigned short* xr = (unsigned short*)(ws + ((size_t)72 << 20));
        float* kb  = (float*)(ws + ((size_t)104 << 20));
        float* vb  = (float*)(ws + ((size_t)168 << 20));
        float* srb = (float*)(ws + ((size_t)8   << 20));   // alias xk+xv
        unsigned short* ybf = xr;                          // alias xr
        float* ca = (float*)(ws + ((size_t)232 << 20));    // 1 MiB each, 6 total
        float* cb = ca + (1u << 18);
        float* cp = cb + (1u << 18);
        float* sa = cp + (1u << 18);
        float* sb = sa + (1u << 18);
        float* sp = sb + (1u << 18);

        mix_cast_kernel<<<16384, 256, 0, stream>>>(x, mk, mv, mr, xk, xv, xr);
        gemm_bt<false><<<1024, 256, 0, stream>>>(xk, wkbf, kb);
        gemm_bt<false><<<1024, 256, 0, stream>>>(xv, wvbf, vb);
        gemm_bt<true ><<<1024, 256, 0, stream>>>(xr, wrbf, srb);   // xk,xv dead now
        wkv_chunk<<<1024, 256, 0, stream>>>(kb, vb, td, ca, cb, cp, 4);
        wkv_scan<<<16, 256, 0, stream>>>(ca, cb, cp, td, sa, sb, sp, 4);
        wkv_emit<<<1024, 256, 0, stream>>>(kb, vb, srb, td, tf, sa, sb, sp, ybf, 4);
        gemm_bt<false><<<1024, 256, 0, stream>>>(ybf, wobf, out);
    } else {
        // ---- per-batch path (~82 MiB peak) : 36 dispatches ----
        unsigned short* xk = (unsigned short*)(ws + ((size_t)8  << 20));  // 8 MB
        unsigned short* xv = (unsigned short*)(ws + ((size_t)16 << 20));
        unsigned short* xr = (unsigned short*)(ws + ((size_t)24 << 20));
        float* kb  = (float*)(ws + ((size_t)32 << 20));                   // 16 MB
        float* vb  = (float*)(ws + ((size_t)48 << 20));
        float* srb = (float*)(ws + ((size_t)64 << 20));
        float* ca  = (float*)(ws + ((size_t)80 << 20));                   // 256 KB each
        float* cb  = ca + (1u << 16);
        float* cp  = cb + (1u << 16);
        float* sa  = cp + (1u << 16);
        float* sb  = sa + (1u << 16);
        float* sp  = sb + (1u << 16);
        unsigned short* ybf = xk;

        for (int b = 0; b < B_; ++b) {
            const float* xb = x + (size_t)b * T_ * C_;
            float* outb = out + (size_t)b * T_ * C_;
            mix_cast_kernel<<<4096, 256, 0, stream>>>(xb, mk, mv, mr, xk, xv, xr);
            gemm_bt<false><<<256, 256, 0, stream>>>(xk, wkbf, kb);
            gemm_bt<false><<<256, 256, 0, stream>>>(xv, wvbf, vb);
            gemm_bt<true ><<<256, 256, 0, stream>>>(xr, wrbf, srb);
            wkv_chunk<<<256, 256, 0, stream>>>(kb, vb, td, ca, cb, cp, 1);
            wkv_scan<<<4, 256, 0, stream>>>(ca, cb, cp, td, sa, sb, sp, 1);
            wkv_emit<<<256, 256, 0, stream>>>(kb, vb, srb, td, tf, sa, sb, sp, ybf, 1);
            gemm_bt<false><<<256, 256, 0, stream>>>(ybf, wobf, outb);
        }
    }
}

// Round 17
// 472.465 us; speedup vs baseline: 1.4359x; 1.0126x over previous
//
#include <hip/hip_runtime.h>
#include <hip/hip_bf16.h>
#include <stdint.h>

#define B_ 4
#define T_ 4096
#define C_ 1024
#define D_ 1024
#define NC_ 64   // chunks over T
#define LC_ 64   // chunk length

typedef __bf16 bf16x8 __attribute__((ext_vector_type(8)));
typedef float  f32x4  __attribute__((ext_vector_type(4)));

__device__ __forceinline__ unsigned short f2bf(float f) {
    union { float f; unsigned u; } c; c.f = f;
    return (unsigned short)((c.u + 0x7fffu + ((c.u >> 16) & 1u)) >> 16);  // RNE
}

// global->LDS direct DMA, 16B/lane. LDS dest must be wave-uniform base (+lane*16 by HW).
__device__ __forceinline__ void gload_lds16(const unsigned short* g, unsigned short* l) {
    __builtin_amdgcn_global_load_lds(
        (const __attribute__((address_space(1))) void*)g,
        (__attribute__((address_space(3))) void*)l,
        16, 0, 0);
}

// ---------------- cast fp32 -> bf16 (weights) ----------------
__global__ void cast_bf16_kernel(const float* __restrict__ s, unsigned short* __restrict__ d) {
    int i = blockIdx.x * blockDim.x + threadIdx.x;   // groups of 4; n = 1M elems
    float4 v = *reinterpret_cast<const float4*>(s + ((size_t)i << 2));
    ushort4 o;
    o.x = f2bf(v.x); o.y = f2bf(v.y); o.z = f2bf(v.z); o.w = f2bf(v.w);
    *reinterpret_cast<ushort4*>(d + ((size_t)i << 2)) = o;
}

// ---------------- time-shift mix -> xk/xv/xr bf16 ----------------
__global__ void mix_cast_kernel(const float* __restrict__ x,
                                const float* __restrict__ mk,
                                const float* __restrict__ mv,
                                const float* __restrict__ mr,
                                unsigned short* __restrict__ xk,
                                unsigned short* __restrict__ xv,
                                unsigned short* __restrict__ xr) {
    int i = blockIdx.x * blockDim.x + threadIdx.x;   // groups of 4 elems
    int base = i << 2;
    int c = base & (C_ - 1);
    int m = base >> 10;          // row within this launch's region
    int t = m & (T_ - 1);        // row within batch
    float4 xc = *reinterpret_cast<const float4*>(x + base);
    float4 xp = make_float4(0.f, 0.f, 0.f, 0.f);
    if (t != 0) xp = *reinterpret_cast<const float4*>(x + base - C_);
    float4 k4 = *reinterpret_cast<const float4*>(mk + c);
    float4 v4 = *reinterpret_cast<const float4*>(mv + c);
    float4 r4 = *reinterpret_cast<const float4*>(mr + c);
    ushort4 ok, ov, orr;
    ok.x  = f2bf(xp.x + k4.x * (xc.x - xp.x));
    ok.y  = f2bf(xp.y + k4.y * (xc.y - xp.y));
    ok.z  = f2bf(xp.z + k4.z * (xc.z - xp.z));
    ok.w  = f2bf(xp.w + k4.w * (xc.w - xp.w));
    ov.x  = f2bf(xp.x + v4.x * (xc.x - xp.x));
    ov.y  = f2bf(xp.y + v4.y * (xc.y - xp.y));
    ov.z  = f2bf(xp.z + v4.z * (xc.z - xp.z));
    ov.w  = f2bf(xp.w + v4.w * (xc.w - xp.w));
    orr.x = f2bf(xp.x + r4.x * (xc.x - xp.x));
    orr.y = f2bf(xp.y + r4.y * (xc.y - xp.y));
    orr.z = f2bf(xp.z + r4.z * (xc.z - xp.z));
    orr.w = f2bf(xp.w + r4.w * (xc.w - xp.w));
    *reinterpret_cast<ushort4*>(xk + base) = ok;
    *reinterpret_cast<ushort4*>(xv + base) = ov;
    *reinterpret_cast<ushort4*>(xr + base) = orr;
}

// ---------------- bt-GEMM: C[m][n] = sum_k A[m][k]*Bw[n][k] ----------------
// A: [16384][1024] bf16, Bw: [1024][1024] bf16, C: fp32. 128x128 tile, BK=32, 4 waves.
// Staging: global_load_lds width-16 (m97 pattern). XCD swizzle: blockIdx%8 = xcd owns
// bm range [xcd*16,+16), bn fastest -> A-panel L2 reuse within one XCD.
template<bool SIG>
__global__ __launch_bounds__(256) void gemm_bt(const unsigned short* __restrict__ A,
                                               const unsigned short* __restrict__ Bw,
                                               float* __restrict__ Cm) {
    __shared__ __align__(16) unsigned short As[128 * 32];
    __shared__ __align__(16) unsigned short Bs[128 * 32];
    const int tid  = threadIdx.x;
    const int lane = tid & 63;
    const int wid  = tid >> 6;
    const int xcd   = blockIdx.x & 7;
    const int local = blockIdx.x >> 3;               // 0..127
    const int bm = (((xcd << 4) + (local >> 3))) << 7;  // 128 bm-tiles, 16 per XCD
    const int bn = (local & 7) << 7;                    // 8 bn-tiles
    const int wr = (wid >> 1) * 64;
    const int wc = (wid & 1) * 64;

    f32x4 acc[4][4] = {};

    // staging addresses: flat tid covers LDS bytes tid*16; row r0 = tid>>2, chunk ck
    const int r0 = tid >> 2;
    const int ck = (tid & 3) * 8;
    const unsigned short* ga0 = A  + (size_t)(bm + r0) * 1024 + ck;
    const unsigned short* gb0 = Bw + (size_t)(bn + r0) * 1024 + ck;
    const unsigned short* ga1 = ga0 + (size_t)64 * 1024;
    const unsigned short* gb1 = gb0 + (size_t)64 * 1024;
    unsigned short* lA0 = As + wid * 512;            // wave-uniform LDS base (1024B/wave)
    unsigned short* lA1 = As + 2048 + wid * 512;     // +64 rows
    unsigned short* lB0 = Bs + wid * 512;
    unsigned short* lB1 = Bs + 2048 + wid * 512;

    const int arow = wr + (lane & 15);
    const int brow = wc + (lane & 15);
    const int ko   = (lane >> 4) * 8;

    for (int ks = 0; ks < 32; ++ks) {
        __syncthreads();
        gload_lds16(ga0, lA0);
        gload_lds16(ga1, lA1);
        gload_lds16(gb0, lB0);
        gload_lds16(gb1, lB1);
        ga0 += 32; ga1 += 32; gb0 += 32; gb1 += 32;
        asm volatile("s_waitcnt vmcnt(0)" ::: "memory");
        __syncthreads();

        bf16x8 af[4], bfr[4];
        #pragma unroll
        for (int i = 0; i < 4; ++i) {
            af[i]  = *reinterpret_cast<const bf16x8*>(&As[(arow + i * 16) * 32 + ko]);
            bfr[i] = *reinterpret_cast<const bf16x8*>(&Bs[(brow + i * 16) * 32 + ko]);
        }
        #pragma unroll
        for (int i = 0; i < 4; ++i)
            #pragma unroll
            for (int j = 0; j < 4; ++j)
                acc[i][j] = __builtin_amdgcn_mfma_f32_16x16x32_bf16(af[i], bfr[j], acc[i][j], 0, 0, 0);
    }

    const int row0 = bm + wr + (lane >> 4) * 4;
    const int col0 = bn + wc + (lane & 15);
    #pragma unroll
    for (int i = 0; i < 4; ++i)
        #pragma unroll
        for (int j = 0; j < 4; ++j)
            #pragma unroll
            for (int r = 0; r < 4; ++r) {
                float vv = acc[i][j][r];
                if (SIG) vv = 1.0f / (1.0f + __expf(-vv));
                Cm[(size_t)(row0 + i * 16 + r) * 1024 + col0 + j * 16] = vv;
            }
}

// ---------------- WKV pass A: per-chunk contribution (init 0,0,-inf) ----------------
__global__ void wkv_chunk(const float* __restrict__ k, const float* __restrict__ v,
                          const float* __restrict__ td,
                          float* __restrict__ ca, float* __restrict__ cb, float* __restrict__ cp,
                          int NB) {
    int gid = blockIdx.x * 256 + threadIdx.x;  // NB*NC*D threads
    int d   = gid & (D_ - 1);
    int rem = gid >> 10;
    int j   = rem & (NC_ - 1);
    int b   = rem >> 6;
    float w = -__expf(td[d]);
    size_t base = ((size_t)(b * T_ + j * LC_)) * D_ + d;
    float aa = 0.f, bb = 0.f, pp = -1e38f;
    for (int t = 0; t < LC_; ++t) {
        float kt = k[base + (size_t)t * D_];
        float vt = v[base + (size_t)t * D_];
        float ww = pp + w;
        float p  = fmaxf(ww, kt);
        float e1 = __expf(ww - p);
        float e2 = __expf(kt - p);
        aa = e1 * aa + e2 * vt;
        bb = e1 * bb + e2;
        pp = p;
    }
    int ch  = (b << 10) + d;
    int idx = j * (NB << 10) + ch;
    ca[idx] = aa;
    cb[idx] = bb;
    cp[idx] = pp;
}

// ---------------- WKV pass B: combine over chunks, store chunk-entry states ----------
__global__ void wkv_scan(const float* __restrict__ ca, const float* __restrict__ cb,
                         const float* __restrict__ cp, const float* __restrict__ td,
                         float* __restrict__ sa, float* __restrict__ sb, float* __restrict__ sp,
                         int NB) {
    int ch = blockIdx.x * 256 + threadIdx.x;  // NB*D channels
    int d  = ch & (D_ - 1);
    float w  = -__expf(td[d]);
    float wL = w * (float)LC_;
    float A = 0.f, Bv = 0.f, P = -1e38f;
    int stride = NB << 10;
    for (int j = 0; j < NC_; ++j) {
        int idx = j * stride + ch;
        sa[idx] = A; sb[idx] = Bv; sp[idx] = P;
        float a2 = ca[idx], b2 = cb[idx], p2 = cp[idx];
        float Pd = P + wL;                    // decay state across a whole chunk
        float pm = fmaxf(Pd, p2);
        float e1 = __expf(Pd - pm);
        float e2 = __expf(p2 - pm);
        A  = e1 * A  + e2 * a2;
        Bv = e1 * Bv + e2 * b2;
        P  = pm;
    }
}

// ---------------- WKV pass C: emit y = sr * wkv as bf16 ----------------
__global__ void wkv_emit(const float* __restrict__ k, const float* __restrict__ v,
                         const float* __restrict__ sr, const float* __restrict__ td,
                         const float* __restrict__ tf,
                         const float* __restrict__ sa, const float* __restrict__ sb,
                         const float* __restrict__ sp,
                         unsigned short* __restrict__ ybf, int NB) {
    int gid = blockIdx.x * 256 + threadIdx.x;
    int d   = gid & (D_ - 1);
    int rem = gid >> 10;
    int j   = rem & (NC_ - 1);
    int b   = rem >> 6;
    int ch  = (b << 10) + d;
    float w = -__expf(td[d]);
    float u = tf[d];
    int idx = j * (NB << 10) + ch;
    float aa = sa[idx], bb = sb[idx], pp = sp[idx];
    size_t base = ((size_t)(b * T_ + j * LC_)) * D_ + d;
    for (int t = 0; t < LC_; ++t) {
        size_t o = base + (size_t)t * D_;
        float kt = k[o];
        float vt = v[o];
        float ww = u + kt;
        float p  = fmaxf(pp, ww);
        float e1 = __expf(pp - p);
        float e2 = __expf(ww - p);
        float y  = (e1 * aa + e2 * vt) / (e1 * bb + e2);
        ybf[o] = f2bf(sr[o] * y);
        float ww2 = pp + w;
        float p2  = fmaxf(ww2, kt);
        float e1b = __expf(ww2 - p2);
        float e2b = __expf(kt - p2);
        aa = e1b * aa + e2b * vt;
        bb = e1b * bb + e2b;
        pp = p2;
    }
}

extern "C" void kernel_launch(void* const* d_in, const int* in_sizes, int n_in,
                              void* d_out, int out_size, void* d_ws, size_t ws_size,
                              hipStream_t stream) {
    const float* x  = (const float*)d_in[0];
    const float* td = (const float*)d_in[1];
    const float* tf = (const float*)d_in[2];
    const float* mk = (const float*)d_in[3];
    const float* mv = (const float*)d_in[4];
    const float* mr = (const float*)d_in[5];
    const float* Wk = (const float*)d_in[6];
    const float* Wv = (const float*)d_in[7];
    const float* Wr = (const float*)d_in[8];
    const float* Wo = (const float*)d_in[9];
    float* out = (float*)d_out;

    char* ws = (char*)d_ws;
    unsigned short* wkbf = (unsigned short*)(ws + ((size_t)0 << 20));
    unsigned short* wvbf = (unsigned short*)(ws + ((size_t)2 << 20));
    unsigned short* wrbf = (unsigned short*)(ws + ((size_t)4 << 20));
    unsigned short* wobf = (unsigned short*)(ws + ((size_t)6 << 20));

    cast_bf16_kernel<<<1024, 256, 0, stream>>>(Wk, wkbf);
    cast_bf16_kernel<<<1024, 256, 0, stream>>>(Wv, wvbf);
    cast_bf16_kernel<<<1024, 256, 0, stream>>>(Wr, wrbf);
    cast_bf16_kernel<<<1024, 256, 0, stream>>>(Wo, wobf);

    if (ws_size >= ((size_t)240 << 20)) {
        // ---- full-batch path, 238 MiB peak via aliasing : 12 dispatches ----
        unsigned short* xk = (unsigned short*)(ws + ((size_t)8  << 20));
        unsigned short* xv = (unsigned short*)(ws + ((size_t)40 << 20));
        unsigned short* xr = (unsigned short*)(ws + ((size_t)72 << 20));
        float* kb  = (float*)(ws + ((size_t)104 << 20));
        float* vb  = (float*)(ws + ((size_t)168 << 20));
        float* srb = (float*)(ws + ((size_t)8   << 20));   // alias xk+xv
        unsigned short* ybf = xr;                          // alias xr
        float* ca = (float*)(ws + ((size_t)232 << 20));    // 1 MiB each, 6 total
        float* cb = ca + (1u << 18);
        float* cp = cb + (1u << 18);
        float* sa = cp + (1u << 18);
        float* sb = sa + (1u << 18);
        float* sp = sb + (1u << 18);

        mix_cast_kernel<<<16384, 256, 0, stream>>>(x, mk, mv, mr, xk, xv, xr);
        gemm_bt<false><<<1024, 256, 0, stream>>>(xk, wkbf, kb);
        gemm_bt<false><<<1024, 256, 0, stream>>>(xv, wvbf, vb);
        gemm_bt<true ><<<1024, 256, 0, stream>>>(xr, wrbf, srb);   // xk,xv dead now
        wkv_chunk<<<1024, 256, 0, stream>>>(kb, vb, td, ca, cb, cp, 4);
        wkv_scan<<<16, 256, 0, stream>>>(ca, cb, cp, td, sa, sb, sp, 4);
        wkv_emit<<<1024, 256, 0, stream>>>(kb, vb, srb, td, tf, sa, sb, sp, ybf, 4);
        gemm_bt<false><<<1024, 256, 0, stream>>>(ybf, wobf, out);
    } else {
        // ---- per-batch path (~82 MiB peak) : 36 dispatches ----
        unsigned short* xk = (unsigned short*)(ws + ((size_t)8  << 20));  // 8 MB
        unsigned short* xv = (unsigned short*)(ws + ((size_t)16 << 20));
        unsigned short* xr = (unsigned short*)(ws + ((size_t)24 << 20));
        float* kb  = (float*)(ws + ((size_t)32 << 20));                   // 16 MB
        float* vb  = (float*)(ws + ((size_t)48 << 20));
        float* srb = (float*)(ws + ((size_t)64 << 20));
        float* ca  = (float*)(ws + ((size_t)80 << 20));                   // 256 KB each
        float* cb  = ca + (1u << 16);
        float* cp  = cb + (1u << 16);
        float* sa  = cp + (1u << 16);
        float* sb  = sa + (1u << 16);
        float* sp  = sb + (1u << 16);
        unsigned short* ybf = xk;

        for (int b = 0; b < B_; ++b) {
            const float* xb = x + (size_t)b * T_ * C_;
            float* outb = out + (size_t)b * T_ * C_;
            mix_cast_kernel<<<4096, 256, 0, stream>>>(xb, mk, mv, mr, xk, xv, xr);
            gemm_bt<false><<<256, 256, 0, stream>>>(xk, wkbf, kb);
            gemm_bt<false><<<256, 256, 0, stream>>>(xv, wvbf, vb);
            gemm_bt<true ><<<256, 256, 0, stream>>>(xr, wrbf, srb);
            wkv_chunk<<<256, 256, 0, stream>>>(kb, vb, td, ca, cb, cp, 1);
            wkv_scan<<<4, 256, 0, stream>>>(ca, cb, cp, td, sa, sb, sp, 1);
            wkv_emit<<<256, 256, 0, stream>>>(kb, vb, srb, td, tf, sa, sb, sp, ybf, 1);
            gemm_bt<false><<<256, 256, 0, stream>>>(ybf, wobf, outb);
        }
    }
}

// Round 18
// 459.054 us; speedup vs baseline: 1.4779x; 1.0292x over previous
//
#include <hip/hip_runtime.h>
#include <hip/hip_bf16.h>
#include <stdint.h>

#define B_ 4
#define T_ 4096
#define C_ 1024
#define D_ 1024
#define NC_ 64   // chunks over T
#define LC_ 64   // chunk length

typedef __bf16 bf16x8 __attribute__((ext_vector_type(8)));
typedef float  f32x4  __attribute__((ext_vector_type(4)));

__device__ __forceinline__ unsigned short f2bf(float f) {
    union { float f; unsigned u; } c; c.f = f;
    return (unsigned short)((c.u + 0x7fffu + ((c.u >> 16) & 1u)) >> 16);  // RNE
}

// global->LDS direct DMA, 16B/lane. LDS dest must be wave-uniform base (+lane*16 by HW).
__device__ __forceinline__ void gload_lds16(const unsigned short* g, unsigned short* l) {
    __builtin_amdgcn_global_load_lds(
        (const __attribute__((address_space(1))) void*)g,
        (__attribute__((address_space(3))) void*)l,
        16, 0, 0);
}

// ---------------- cast fp32 -> bf16 (weights) ----------------
__global__ void cast_bf16_kernel(const float* __restrict__ s, unsigned short* __restrict__ d) {
    int i = blockIdx.x * blockDim.x + threadIdx.x;
    float4 v = *reinterpret_cast<const float4*>(s + ((size_t)i << 2));
    ushort4 o;
    o.x = f2bf(v.x); o.y = f2bf(v.y); o.z = f2bf(v.z); o.w = f2bf(v.w);
    *reinterpret_cast<ushort4*>(d + ((size_t)i << 2)) = o;
}

// ---------------- time-shift mix -> xk/xv/xr bf16 ----------------
__global__ void mix_cast_kernel(const float* __restrict__ x,
                                const float* __restrict__ mk,
                                const float* __restrict__ mv,
                                const float* __restrict__ mr,
                                unsigned short* __restrict__ xk,
                                unsigned short* __restrict__ xv,
                                unsigned short* __restrict__ xr) {
    int i = blockIdx.x * blockDim.x + threadIdx.x;
    int base = i << 2;
    int c = base & (C_ - 1);
    int m = base >> 10;
    int t = m & (T_ - 1);
    float4 xc = *reinterpret_cast<const float4*>(x + base);
    float4 xp = make_float4(0.f, 0.f, 0.f, 0.f);
    if (t != 0) xp = *reinterpret_cast<const float4*>(x + base - C_);
    float4 k4 = *reinterpret_cast<const float4*>(mk + c);
    float4 v4 = *reinterpret_cast<const float4*>(mv + c);
    float4 r4 = *reinterpret_cast<const float4*>(mr + c);
    ushort4 ok, ov, orr;
    ok.x  = f2bf(xp.x + k4.x * (xc.x - xp.x));
    ok.y  = f2bf(xp.y + k4.y * (xc.y - xp.y));
    ok.z  = f2bf(xp.z + k4.z * (xc.z - xp.z));
    ok.w  = f2bf(xp.w + k4.w * (xc.w - xp.w));
    ov.x  = f2bf(xp.x + v4.x * (xc.x - xp.x));
    ov.y  = f2bf(xp.y + v4.y * (xc.y - xp.y));
    ov.z  = f2bf(xp.z + v4.z * (xc.z - xp.z));
    ov.w  = f2bf(xp.w + v4.w * (xc.w - xp.w));
    orr.x = f2bf(xp.x + r4.x * (xc.x - xp.x));
    orr.y = f2bf(xp.y + r4.y * (xc.y - xp.y));
    orr.z = f2bf(xp.z + r4.z * (xc.z - xp.z));
    orr.w = f2bf(xp.w + r4.w * (xc.w - xp.w));
    *reinterpret_cast<ushort4*>(xk + base) = ok;
    *reinterpret_cast<ushort4*>(xv + base) = ov;
    *reinterpret_cast<ushort4*>(xr + base) = orr;
}

// ---------------- bt-GEMM: C[m][n] = sum_k A[m][k]*Bw[n][k] ----------------
// 128x128 tile, BK=32, 4 waves. global_load_lds staging, 2-phase LDS double-buffer
// with raw s_barrier (counted overlap: prefetch issued before compute, one
// vmcnt(0)+barrier per K-step). XCD swizzle: blockIdx&7 owns a bm range.
// LDS bank fix: chunk-XOR s(r)=(r&3)^((r>>2)&3) pre-applied on the GLOBAL source
// (gload_lds dest stays linear) and mirrored on the ds_read chunk -> 2-way (free).
template<bool SIG>
__global__ __launch_bounds__(256) void gemm_bt(const unsigned short* __restrict__ A,
                                               const unsigned short* __restrict__ Bw,
                                               float* __restrict__ Cm) {
    __shared__ __align__(16) unsigned short As[2][4096];
    __shared__ __align__(16) unsigned short Bs[2][4096];
    const int tid  = threadIdx.x;
    const int lane = tid & 63;
    const int wid  = tid >> 6;
    const int xcd   = blockIdx.x & 7;
    const int local = blockIdx.x >> 3;                  // 0..127
    const int bm = ((xcd << 4) + (local >> 3)) << 7;    // 16 bm-tiles per XCD
    const int bn = (local & 7) << 7;
    const int wr = (wid >> 1) * 64;
    const int wc = (wid & 1) * 64;

    f32x4 acc[4][4] = {};

    // staging: thread tid -> LDS row r0=tid>>2, chunk tid&3 (linear dest).
    // Global source chunk is XOR-swizzled so LDS(r,c) = global(r, c^s(r)).
    const int r0 = tid >> 2;
    const int sw = (r0 & 3) ^ ((r0 >> 2) & 3);
    const int ck = (((tid & 3) ^ sw) * 8);              // ushorts
    const unsigned short* ga0 = A  + (size_t)(bm + r0) * 1024 + ck;
    const unsigned short* gb0 = Bw + (size_t)(bn + r0) * 1024 + ck;
    const unsigned short* ga1 = ga0 + (size_t)64 * 1024;
    const unsigned short* gb1 = gb0 + (size_t)64 * 1024;
    const int wofs = wid * 512;                         // ushorts; wave-uniform LDS base

    const int arow = wr + (lane & 15);
    const int brow = wc + (lane & 15);
    const int sr   = (lane & 3) ^ ((lane >> 2) & 3);    // s(row) for row=(lane&15)+16i
    const int ko   = (((lane >> 4) ^ sr) * 8);          // swizzled ds_read chunk

    // prologue: stage K-step 0 into buffer 0
    gload_lds16(ga0, &As[0][wofs]);
    gload_lds16(ga1, &As[0][2048 + wofs]);
    gload_lds16(gb0, &Bs[0][wofs]);
    gload_lds16(gb1, &Bs[0][2048 + wofs]);
    ga0 += 32; ga1 += 32; gb0 += 32; gb1 += 32;
    asm volatile("s_waitcnt vmcnt(0)" ::: "memory");
    __builtin_amdgcn_s_barrier();

    int cur = 0;
    for (int ks = 0; ks < 32; ++ks) {
        if (ks < 31) {   // issue next-tile loads BEFORE computing current tile
            gload_lds16(ga0, &As[cur ^ 1][wofs]);
            gload_lds16(ga1, &As[cur ^ 1][2048 + wofs]);
            gload_lds16(gb0, &Bs[cur ^ 1][wofs]);
            gload_lds16(gb1, &Bs[cur ^ 1][2048 + wofs]);
            ga0 += 32; ga1 += 32; gb0 += 32; gb1 += 32;
        }
        bf16x8 af[4], bfr[4];
        #pragma unroll
        for (int i = 0; i < 4; ++i) {
            af[i]  = *reinterpret_cast<const bf16x8*>(&As[cur][(arow + i * 16) * 32 + ko]);
            bfr[i] = *reinterpret_cast<const bf16x8*>(&Bs[cur][(brow + i * 16) * 32 + ko]);
        }
        #pragma unroll
        for (int i = 0; i < 4; ++i)
            #pragma unroll
            for (int j = 0; j < 4; ++j)
                acc[i][j] = __builtin_amdgcn_mfma_f32_16x16x32_bf16(af[i], bfr[j], acc[i][j], 0, 0, 0);
        // prefetch landed + all waves done reading buf[cur] -> safe to swap
        asm volatile("s_waitcnt vmcnt(0)" ::: "memory");
        __builtin_amdgcn_s_barrier();
        cur ^= 1;
    }

    const int row0 = bm + wr + (lane >> 4) * 4;
    const int col0 = bn + wc + (lane & 15);
    #pragma unroll
    for (int i = 0; i < 4; ++i)
        #pragma unroll
        for (int j = 0; j < 4; ++j)
            #pragma unroll
            for (int r = 0; r < 4; ++r) {
                float vv = acc[i][j][r];
                if (SIG) vv = 1.0f / (1.0f + __expf(-vv));
                Cm[(size_t)(row0 + i * 16 + r) * 1024 + col0 + j * 16] = vv;
            }
}

// ---------------- WKV pass A: per-chunk contribution (init 0,0,-inf) ----------------
__global__ void wkv_chunk(const float* __restrict__ k, const float* __restrict__ v,
                          const float* __restrict__ td,
                          float* __restrict__ ca, float* __restrict__ cb, float* __restrict__ cp,
                          int NB) {
    int gid = blockIdx.x * 256 + threadIdx.x;
    int d   = gid & (D_ - 1);
    int rem = gid >> 10;
    int j   = rem & (NC_ - 1);
    int b   = rem >> 6;
    float w = -__expf(td[d]);
    size_t base = ((size_t)(b * T_ + j * LC_)) * D_ + d;
    float aa = 0.f, bb = 0.f, pp = -1e38f;
    for (int t = 0; t < LC_; ++t) {
        float kt = k[base + (size_t)t * D_];
        float vt = v[base + (size_t)t * D_];
        float ww = pp + w;
        float p  = fmaxf(ww, kt);
        float e1 = __expf(ww - p);
        float e2 = __expf(kt - p);
        aa = e1 * aa + e2 * vt;
        bb = e1 * bb + e2;
        pp = p;
    }
    int ch  = (b << 10) + d;
    int idx = j * (NB << 10) + ch;
    ca[idx] = aa;
    cb[idx] = bb;
    cp[idx] = pp;
}

// ---------------- WKV pass B: combine over chunks, store chunk-entry states ----------
__global__ void wkv_scan(const float* __restrict__ ca, const float* __restrict__ cb,
                         const float* __restrict__ cp, const float* __restrict__ td,
                         float* __restrict__ sa, float* __restrict__ sb, float* __restrict__ sp,
                         int NB) {
    int ch = blockIdx.x * 256 + threadIdx.x;
    int d  = ch & (D_ - 1);
    float w  = -__expf(td[d]);
    float wL = w * (float)LC_;
    float A = 0.f, Bv = 0.f, P = -1e38f;
    int stride = NB << 10;
    for (int j = 0; j < NC_; ++j) {
        int idx = j * stride + ch;
        sa[idx] = A; sb[idx] = Bv; sp[idx] = P;
        float a2 = ca[idx], b2 = cb[idx], p2 = cp[idx];
        float Pd = P + wL;
        float pm = fmaxf(Pd, p2);
        float e1 = __expf(Pd - pm);
        float e2 = __expf(p2 - pm);
        A  = e1 * A  + e2 * a2;
        Bv = e1 * Bv + e2 * b2;
        P  = pm;
    }
}

// ---------------- WKV pass C: emit y = sr * wkv as bf16 ----------------
__global__ void wkv_emit(const float* __restrict__ k, const float* __restrict__ v,
                         const float* __restrict__ sr, const float* __restrict__ td,
                         const float* __restrict__ tf,
                         const float* __restrict__ sa, const float* __restrict__ sb,
                         const float* __restrict__ sp,
                         unsigned short* __restrict__ ybf, int NB) {
    int gid = blockIdx.x * 256 + threadIdx.x;
    int d   = gid & (D_ - 1);
    int rem = gid >> 10;
    int j   = rem & (NC_ - 1);
    int b   = rem >> 6;
    int ch  = (b << 10) + d;
    float w = -__expf(td[d]);
    float u = tf[d];
    int idx = j * (NB << 10) + ch;
    float aa = sa[idx], bb = sb[idx], pp = sp[idx];
    size_t base = ((size_t)(b * T_ + j * LC_)) * D_ + d;
    for (int t = 0; t < LC_; ++t) {
        size_t o = base + (size_t)t * D_;
        float kt = k[o];
        float vt = v[o];
        float ww = u + kt;
        float p  = fmaxf(pp, ww);
        float e1 = __expf(pp - p);
        float e2 = __expf(ww - p);
        float y  = (e1 * aa + e2 * vt) / (e1 * bb + e2);
        ybf[o] = f2bf(sr[o] * y);
        float ww2 = pp + w;
        float p2  = fmaxf(ww2, kt);
        float e1b = __expf(ww2 - p2);
        float e2b = __expf(kt - p2);
        aa = e1b * aa + e2b * vt;
        bb = e1b * bb + e2b;
        pp = p2;
    }
}

extern "C" void kernel_launch(void* const* d_in, const int* in_sizes, int n_in,
                              void* d_out, int out_size, void* d_ws, size_t ws_size,
                              hipStream_t stream) {
    const float* x  = (const float*)d_in[0];
    const float* td = (const float*)d_in[1];
    const float* tf = (const float*)d_in[2];
    const float* mk = (const float*)d_in[3];
    const float* mv = (const float*)d_in[4];
    const float* mr = (const float*)d_in[5];
    const float* Wk = (const float*)d_in[6];
    const float* Wv = (const float*)d_in[7];
    const float* Wr = (const float*)d_in[8];
    const float* Wo = (const float*)d_in[9];
    float* out = (float*)d_out;

    char* ws = (char*)d_ws;
    unsigned short* wkbf = (unsigned short*)(ws + ((size_t)0 << 20));
    unsigned short* wvbf = (unsigned short*)(ws + ((size_t)2 << 20));
    unsigned short* wrbf = (unsigned short*)(ws + ((size_t)4 << 20));
    unsigned short* wobf = (unsigned short*)(ws + ((size_t)6 << 20));

    cast_bf16_kernel<<<1024, 256, 0, stream>>>(Wk, wkbf);
    cast_bf16_kernel<<<1024, 256, 0, stream>>>(Wv, wvbf);
    cast_bf16_kernel<<<1024, 256, 0, stream>>>(Wr, wrbf);
    cast_bf16_kernel<<<1024, 256, 0, stream>>>(Wo, wobf);

    if (ws_size >= ((size_t)240 << 20)) {
        // ---- full-batch path, 238 MiB peak via aliasing : 12 dispatches ----
        unsigned short* xk = (unsigned short*)(ws + ((size_t)8  << 20));
        unsigned short* xv = (unsigned short*)(ws + ((size_t)40 << 20));
        unsigned short* xr = (unsigned short*)(ws + ((size_t)72 << 20));
        float* kb  = (float*)(ws + ((size_t)104 << 20));
        float* vb  = (float*)(ws + ((size_t)168 << 20));
        float* srb = (float*)(ws + ((size_t)8   << 20));   // alias xk+xv
        unsigned short* ybf = xr;                          // alias xr
        float* ca = (float*)(ws + ((size_t)232 << 20));
        float* cb = ca + (1u << 18);
        float* cp = cb + (1u << 18);
        float* sa = cp + (1u << 18);
        float* sb = sa + (1u << 18);
        float* sp = sb + (1u << 18);

        mix_cast_kernel<<<16384, 256, 0, stream>>>(x, mk, mv, mr, xk, xv, xr);
        gemm_bt<false><<<1024, 256, 0, stream>>>(xk, wkbf, kb);
        gemm_bt<false><<<1024, 256, 0, stream>>>(xv, wvbf, vb);
        gemm_bt<true ><<<1024, 256, 0, stream>>>(xr, wrbf, srb);   // xk,xv dead now
        wkv_chunk<<<1024, 256, 0, stream>>>(kb, vb, td, ca, cb, cp, 4);
        wkv_scan<<<16, 256, 0, stream>>>(ca, cb, cp, td, sa, sb, sp, 4);
        wkv_emit<<<1024, 256, 0, stream>>>(kb, vb, srb, td, tf, sa, sb, sp, ybf, 4);
        gemm_bt<false><<<1024, 256, 0, stream>>>(ybf, wobf, out);
    } else {
        // ---- per-batch path (~82 MiB peak) : 36 dispatches ----
        unsigned short* xk = (unsigned short*)(ws + ((size_t)8  << 20));
        unsigned short* xv = (unsigned short*)(ws + ((size_t)16 << 20));
        unsigned short* xr = (unsigned short*)(ws + ((size_t)24 << 20));
        float* kb  = (float*)(ws + ((size_t)32 << 20));
        float* vb  = (float*)(ws + ((size_t)48 << 20));
        float* srb = (float*)(ws + ((size_t)64 << 20));
        float* ca  = (float*)(ws + ((size_t)80 << 20));
        float* cb  = ca + (1u << 16);
        float* cp  = cb + (1u << 16);
        float* sa  = cp + (1u << 16);
        float* sb  = sa + (1u << 16);
        float* sp  = sb + (1u << 16);
        unsigned short* ybf = xk;

        for (int b = 0; b < B_; ++b) {
            const float* xb = x + (size_t)b * T_ * C_;
            float* outb = out + (size_t)b * T_ * C_;
            mix_cast_kernel<<<4096, 256, 0, stream>>>(xb, mk, mv, mr, xk, xv, xr);
            gemm_bt<false><<<256, 256, 0, stream>>>(xk, wkbf, kb);
            gemm_bt<false><<<256, 256, 0, stream>>>(xv, wvbf, vb);
            gemm_bt<true ><<<256, 256, 0, stream>>>(xr, wrbf, srb);
            wkv_chunk<<<256, 256, 0, stream>>>(kb, vb, td, ca, cb, cp, 1);
            wkv_scan<<<4, 256, 0, stream>>>(ca, cb, cp, td, sa, sb, sp, 1);
            wkv_emit<<<256, 256, 0, stream>>>(kb, vb, srb, td, tf, sa, sb, sp, ybf, 1);
            gemm_bt<false><<<256, 256, 0, stream>>>(ybf, wobf, outb);
        }
    }
}